// Round 17
// baseline (131.653 us; speedup 1.0000x reference)
//
#include <hip/hip_runtime.h>
#include <hip/hip_bf16.h>

#define PIX 256
#define CROP 14
#define HW2 196
#define BB 128
#define CC 512
#define NC 384
#define NO 768
#define CAP 128

typedef __bf16 bf16x8 __attribute__((ext_vector_type(8)));
typedef __bf16 bf16x4 __attribute__((ext_vector_type(4)));
typedef float  f32x4  __attribute__((ext_vector_type(4)));
typedef unsigned int u32;

#define GLOAD_LDS16(src, dst) \
    __builtin_amdgcn_global_load_lds((const __attribute__((address_space(1))) void*)(src), \
                                     (__attribute__((address_space(3))) void*)(dst), 16, 0, 0)

// wconv + cnt zeroing fused
__global__ void wconv_kernel(const float* __restrict__ W, __bf16* __restrict__ Wb,
                             int* __restrict__ cnt) {
    int tid = blockIdx.x * 256 + threadIdx.x;
    Wb[tid] = (__bf16)W[tid];
    if (tid < 1536) cnt[tid] = 0;
}

// entry word: (c3loc<<25) | (hw<<17) | (p<<9) | ch ; bucket = t*512 + ch
__global__ void fill_kernel(const int* __restrict__ idx, const int* __restrict__ offh,
                            const int* __restrict__ offw, int* __restrict__ cnt,
                            u32* __restrict__ bucket) {
    int tid = blockIdx.x * 256 + threadIdx.x;   // < 75264
    int c3 = tid / HW2;
    int hw = tid - c3 * HW2;
    int i = hw / CROP, j = hw - i * CROP;
    int p = (offh[c3] + i) * 16 + offw[c3] + j;
    int ch = idx[c3 * PIX + p];
    int bkt = (c3 >> 7) * 512 + ch;
    int pos = atomicAdd(&cnt[bkt], 1);
    if (pos < CAP)
        bucket[bkt * CAP + pos] =
            ((u32)(c3 & 127) << 25) | ((u32)hw << 17) | ((u32)p << 9) | (u32)ch;
}

// exclusive prefix over 1536 clamped counts (single block, 6 per thread)
__global__ __launch_bounds__(256) void scan_kernel(const int* __restrict__ cnt,
                                                   int* __restrict__ pref) {
    __shared__ int part[256];
    int tid = threadIdx.x;
    int loc[6];
    int s = 0;
#pragma unroll
    for (int i = 0; i < 6; ++i) {
        int v = cnt[tid * 6 + i]; if (v > CAP) v = CAP;
        loc[i] = s; s += v;
    }
    part[tid] = s;
    __syncthreads();
    if (tid < 64) {
        int l4[4]; int s4 = 0;
#pragma unroll
        for (int i = 0; i < 4; ++i) { l4[i] = s4; s4 += part[tid * 4 + i]; }
        int v = s4;
#pragma unroll
        for (int d = 1; d < 64; d <<= 1) { int u = __shfl_up(v, d); if (tid >= d) v += u; }
        int excl = v - s4;
#pragma unroll
        for (int i = 0; i < 4; ++i) part[tid * 4 + i] = excl + l4[i];
    }
    __syncthreads();
    int off = part[tid];
#pragma unroll
    for (int i = 0; i < 6; ++i) pref[tid * 6 + i] = off + loc[i];
}

// dense entry list ordered (t, ch)
__global__ __launch_bounds__(128) void compact_kernel(const int* __restrict__ cnt,
                                                      const int* __restrict__ pref,
                                                      const u32* __restrict__ bucket,
                                                      u32* __restrict__ ent) {
    int bkt = blockIdx.x;
    int E = cnt[bkt]; if (E > CAP) E = CAP;
    int tid = threadIdx.x;
    if (tid < E) ent[pref[bkt] + tid] = bucket[bkt * CAP + tid];
}

// scatter v12: SEQUENTIAL + COALESCED staging (the untested combination).
// block = (b, t, ch-octant): streams a CONTIGUOUS 64KB x-window with f32x4
// loads (copy-ubench pattern) into a 32KB bf16 LDS tile, then walks its
// pref-delimited entry slice and fires 2B stores directly into feats
// (non-blocking; L2 merges within the block's 50KB feats region).
__global__ __launch_bounds__(256) void scatter_kernel(
        const float* __restrict__ x1, const float* __restrict__ x3,
        const float* __restrict__ x5, const u32* __restrict__ ent,
        const int* __restrict__ pref, __bf16* __restrict__ feats) {
    __shared__ __bf16 fl[64 * 256];          // 32KB -> 4 blocks/CU
    int d = blockIdx.x;                      // 3072 = 8 XCD * 384
    int wg = (d & 7) * 384 + (d >> 3);
    int b = wg / 24, tq = wg - b * 24;
    int t = tq >> 3, oct = tq & 7;
    const float* x = (t == 0) ? x1 : (t == 1) ? x3 : x5;
    const float* base = x + ((size_t)b * CC + oct * 64) * PIX;
    int tid = threadIdx.x;

    // phase 1: 64KB fully-sequential stage, 16 f32x4 per thread
#pragma unroll 4
    for (int i = 0; i < 16; ++i) {
        int fo = i * 1024 + tid * 4;         // float offset in window
        f32x4 v = *(const f32x4*)(base + fo);
        bf16x4 q;
        q[0] = (__bf16)v[0]; q[1] = (__bf16)v[1];
        q[2] = (__bf16)v[2]; q[3] = (__bf16)v[3];
        *(bf16x4*)&fl[fo] = q;
    }
    __syncthreads();

    // phase 2: entry slice [e0, e1) for (t, ch in [oct*64, oct*64+64))
    int pi = t * 512 + oct * 64;
    int e0 = pref[pi];
    int e1 = (pi + 64 >= 1536) ? 75264 : pref[pi + 64];
    const size_t fb = (size_t)b * HW2 * NC + (size_t)t * 128;
    for (int g = e0 + tid; g < e1; g += 256) {
        u32 wd = ent[g];
        int ch = wd & 511;
        int p  = (wd >> 9) & 255;
        int hw = (wd >> 17) & 255;
        int c3 = wd >> 25;
        feats[fb + (size_t)hw * NC + c3] = fl[(ch & 63) * 256 + p];
    }
}

// GEMM: m97 structure, 128x128 tile, BK=64, XOR-swizzled LDS via pre-swizzled source.
__global__ __launch_bounds__(256) void gemm_kernel(const __bf16* __restrict__ feats,
                                                   const __bf16* __restrict__ Wb,
                                                   float* __restrict__ out) {
    __shared__ __bf16 ldsbuf[16384];           // A [128][64] @0, B [128][64] @8192
    __bf16* Abuf = ldsbuf;
    __bf16* Bbuf = ldsbuf + 8192;

    const int d = blockIdx.x;                  // 1176 blocks, 147 per XCD
    const int wg = (d & 7) * 147 + (d >> 3);
    const int o_base = (wg % 6) * 128;
    const int m_base = (wg / 6) * 128;

    const int tid = threadIdx.x;
    const int wave = tid >> 6, lane = tid & 63;
    const int wo = wave >> 1, wm = wave & 1;
    const int l15 = lane & 15, g = lane >> 4;
    const int xr = l15 & 7;

    f32x4 acc[4][4] = {};

    for (int kt = 0; kt < 6; ++kt) {
        const int k0g = kt * 64;
#pragma unroll
        for (int it = 0; it < 4; ++it) {
            int ck = tid + it * 256;
            int row = ck >> 3, cc = ck & 7;
            int koff = k0g + ((cc ^ (row & 7)) << 3);
            GLOAD_LDS16(Wb    + (size_t)(o_base + row) * NC + koff, Abuf + ck * 8);
            GLOAD_LDS16(feats + (size_t)(m_base + row) * NC + koff, Bbuf + ck * 8);
        }
        __syncthreads();
#pragma unroll
        for (int k0 = 0; k0 < 64; k0 += 32) {
            const int cb = (k0 >> 3) + g;
            bf16x8 a[4], b[4];
#pragma unroll
            for (int s = 0; s < 4; ++s) {
                int arow = wo * 64 + s * 16 + l15;
                a[s] = *(const bf16x8*)&Abuf[arow * 64 + ((cb ^ xr) << 3)];
                int brow = wm * 64 + s * 16 + l15;
                b[s] = *(const bf16x8*)&Bbuf[brow * 64 + ((cb ^ xr) << 3)];
            }
#pragma unroll
            for (int os = 0; os < 4; ++os)
#pragma unroll
                for (int ms = 0; ms < 4; ++ms)
                    acc[os][ms] = __builtin_amdgcn_mfma_f32_16x16x32_bf16(a[os], b[ms], acc[os][ms], 0, 0, 0);
        }
        __syncthreads();
    }

#pragma unroll
    for (int os = 0; os < 4; ++os)
#pragma unroll
        for (int ms = 0; ms < 4; ++ms) {
            int m = m_base + wm * 64 + ms * 16 + l15;
            int bb = m / HW2;
            int hw = m - bb * HW2;
            int o = o_base + wo * 64 + os * 16 + g * 4;
            float* dst = out + ((size_t)bb * NO + o) * HW2 + hw;
            f32x4 v = acc[os][ms];
            dst[0 * HW2] = v[0];
            dst[1 * HW2] = v[1];
            dst[2 * HW2] = v[2];
            dst[3 * HW2] = v[3];
        }
}

extern "C" void kernel_launch(void* const* d_in, const int* in_sizes, int n_in,
                              void* d_out, int out_size, void* d_ws, size_t ws_size,
                              hipStream_t stream) {
    const float* x1   = (const float*)d_in[0];
    const float* x3   = (const float*)d_in[1];
    const float* x5   = (const float*)d_in[2];
    const float* W    = (const float*)d_in[3];
    const int*   idx  = (const int*)d_in[4];
    const int*   offh = (const int*)d_in[5];
    const int*   offw = (const int*)d_in[6];
    float* out = (float*)d_out;

    char* ws = (char*)d_ws;
    __bf16* feats  = (__bf16*)(ws);              // 19,267,584 B
    __bf16* Wb     = (__bf16*)(ws + 19267584);   // 589,824 B
    int*    cnt    = (int*)   (ws + 19857408);   // 6,144 B
    int*    pref   = (int*)   (ws + 19863552);   // 6,144 B
    u32*    bucket = (u32*)   (ws + 19869696);   // 786,432 B
    u32*    ent    = (u32*)   (ws + 20656128);   // 301,056 B

    wconv_kernel<<<(NO * NC) / 256, 256, 0, stream>>>(W, Wb, cnt);
    fill_kernel<<<(NC * HW2) / 256, 256, 0, stream>>>(idx, offh, offw, cnt, bucket);
    scan_kernel<<<1, 256, 0, stream>>>(cnt, pref);
    compact_kernel<<<1536, 128, 0, stream>>>(cnt, pref, bucket, ent);
    scatter_kernel<<<3072, 256, 0, stream>>>(x1, x3, x5, ent, pref, feats);
    gemm_kernel<<<1176, 256, 0, stream>>>(feats, Wb, out);
}

// Round 18
// 110.861 us; speedup vs baseline: 1.1875x; 1.1875x over previous
//
#include <hip/hip_runtime.h>
#include <hip/hip_bf16.h>

#define PIX 256
#define CROP 14
#define HW2 196
#define BB 128
#define CC 512
#define NC 384
#define NO 768
#define CAP 128

typedef __bf16 bf16x8 __attribute__((ext_vector_type(8)));
typedef __bf16 bf16x4 __attribute__((ext_vector_type(4)));
typedef float  f32x4  __attribute__((ext_vector_type(4)));
typedef unsigned int u32;

#define GLOAD_LDS16(src, dst) \
    __builtin_amdgcn_global_load_lds((const __attribute__((address_space(1))) void*)(src), \
                                     (__attribute__((address_space(3))) void*)(dst), 16, 0, 0)

// wconv + cnt zeroing fused
__global__ void wconv_kernel(const float* __restrict__ W, __bf16* __restrict__ Wb,
                             int* __restrict__ cnt) {
    int tid = blockIdx.x * 256 + threadIdx.x;
    Wb[tid] = (__bf16)W[tid];
    if (tid < 1536) cnt[tid] = 0;
}

// entry word: (c3loc<<25) | (hw<<17) | (p<<9) | ch ; bucket = t*512 + ch
__global__ void fill_kernel(const int* __restrict__ idx, const int* __restrict__ offh,
                            const int* __restrict__ offw, int* __restrict__ cnt,
                            u32* __restrict__ bucket) {
    int tid = blockIdx.x * 256 + threadIdx.x;   // < 75264
    int c3 = tid / HW2;
    int hw = tid - c3 * HW2;
    int i = hw / CROP, j = hw - i * CROP;
    int p = (offh[c3] + i) * 16 + offw[c3] + j;
    int ch = idx[c3 * PIX + p];
    int bkt = (c3 >> 7) * 512 + ch;
    int pos = atomicAdd(&cnt[bkt], 1);
    if (pos < CAP)
        bucket[bkt * CAP + pos] =
            ((u32)(c3 & 127) << 25) | ((u32)hw << 17) | ((u32)p << 9) | (u32)ch;
}

// exclusive prefix over 1536 clamped counts (single block, 6 per thread)
__global__ __launch_bounds__(256) void scan_kernel(const int* __restrict__ cnt,
                                                   int* __restrict__ pref) {
    __shared__ int part[256];
    int tid = threadIdx.x;
    int loc[6];
    int s = 0;
#pragma unroll
    for (int i = 0; i < 6; ++i) {
        int v = cnt[tid * 6 + i]; if (v > CAP) v = CAP;
        loc[i] = s; s += v;
    }
    part[tid] = s;
    __syncthreads();
    if (tid < 64) {
        int l4[4]; int s4 = 0;
#pragma unroll
        for (int i = 0; i < 4; ++i) { l4[i] = s4; s4 += part[tid * 4 + i]; }
        int v = s4;
#pragma unroll
        for (int d = 1; d < 64; d <<= 1) { int u = __shfl_up(v, d); if (tid >= d) v += u; }
        int excl = v - s4;
#pragma unroll
        for (int i = 0; i < 4; ++i) part[tid * 4 + i] = excl + l4[i];
    }
    __syncthreads();
    int off = part[tid];
#pragma unroll
    for (int i = 0; i < 6; ++i) pref[tid * 6 + i] = off + loc[i];
}

// dense entry list ordered (t, ch)
__global__ __launch_bounds__(128) void compact_kernel(const int* __restrict__ cnt,
                                                      const int* __restrict__ pref,
                                                      const u32* __restrict__ bucket,
                                                      u32* __restrict__ ent) {
    int bkt = blockIdx.x;
    int E = cnt[bkt]; if (E > CAP) E = CAP;
    int tid = threadIdx.x;
    if (tid < E) ent[pref[bkt] + tid] = bucket[bkt * CAP + tid];
}

// scatter v13: ZERO divergent global accesses. block = (b,t), 512 thr.
// 16 chunks: stream 32 ch-rows (32KB fp32, fully sequential f32x4) -> bf16
// stg LDS; scatter that ch-range's pref-delimited entries LDS->LDS into
// fl[196][128]; coalesced bf16x8 writeout at the end. Global side: 512KB
// sequential read + 50KB coalesced write per block. LDS 66.5KB -> 2 blk/CU.
__global__ __launch_bounds__(512) void scatter_kernel(
        const float* __restrict__ x1, const float* __restrict__ x3,
        const float* __restrict__ x5, const u32* __restrict__ ent,
        const int* __restrict__ pref, __bf16* __restrict__ feats) {
    __shared__ __bf16 fl[HW2 * 128];         // 50176 B
    __shared__ __bf16 stg[32 * 256];         // 16384 B
    int d = blockIdx.x;                      // 384 = 8 XCD * 48
    int wg = (d & 7) * 48 + (d >> 3);
    int b = wg / 3, t = wg % 3;
    const float* x = (t == 0) ? x1 : (t == 1) ? x3 : x5;
    const float* xb = x + (size_t)b * CC * PIX;
    int tid = threadIdx.x;

    for (int ck = 0; ck < 16; ++ck) {
        // stage 32 ch-rows: 512 thr x 4 f32x4, sequential
#pragma unroll
        for (int i = 0; i < 4; ++i) {
            int fo = i * 2048 + tid * 4;     // [0, 8192)
            f32x4 v = *(const f32x4*)(xb + ck * 8192 + fo);
            bf16x4 q;
            q[0] = (__bf16)v[0]; q[1] = (__bf16)v[1];
            q[2] = (__bf16)v[2]; q[3] = (__bf16)v[3];
            *(bf16x4*)&stg[fo] = q;
        }
        __syncthreads();
        // scatter entries with ch in [ck*32, ck*32+32): LDS -> LDS
        int pi = t * 512 + ck * 32;
        int e0 = pref[pi];
        int e1 = (pi + 32 >= 1536) ? 75264 : pref[pi + 32];
        for (int g = e0 + tid; g < e1; g += 512) {
            u32 wd = ent[g];
            int ch = wd & 511;
            int p  = (wd >> 9) & 255;
            int hw = (wd >> 17) & 255;
            int c3 = wd >> 25;
            fl[hw * 128 + c3] = stg[(ch & 31) * 256 + p];
        }
        __syncthreads();
    }

    // coalesced writeout
    const size_t obase = (size_t)b * HW2 * NC + (size_t)t * 128;
    for (int i2 = tid; i2 < HW2 * 16; i2 += 512) {
        int hw = i2 >> 4, ckk = (i2 & 15) * 8;
        *(bf16x8*)(feats + obase + (size_t)hw * NC + ckk) = *(const bf16x8*)&fl[hw * 128 + ckk];
    }
}

// GEMM: m97 structure, 128x128 tile, BK=64, XOR-swizzled LDS via pre-swizzled source.
__global__ __launch_bounds__(256) void gemm_kernel(const __bf16* __restrict__ feats,
                                                   const __bf16* __restrict__ Wb,
                                                   float* __restrict__ out) {
    __shared__ __bf16 ldsbuf[16384];           // A [128][64] @0, B [128][64] @8192
    __bf16* Abuf = ldsbuf;
    __bf16* Bbuf = ldsbuf + 8192;

    const int d = blockIdx.x;                  // 1176 blocks, 147 per XCD
    const int wg = (d & 7) * 147 + (d >> 3);
    const int o_base = (wg % 6) * 128;
    const int m_base = (wg / 6) * 128;

    const int tid = threadIdx.x;
    const int wave = tid >> 6, lane = tid & 63;
    const int wo = wave >> 1, wm = wave & 1;
    const int l15 = lane & 15, g = lane >> 4;
    const int xr = l15 & 7;

    f32x4 acc[4][4] = {};

    for (int kt = 0; kt < 6; ++kt) {
        const int k0g = kt * 64;
#pragma unroll
        for (int it = 0; it < 4; ++it) {
            int ck = tid + it * 256;
            int row = ck >> 3, cc = ck & 7;
            int koff = k0g + ((cc ^ (row & 7)) << 3);
            GLOAD_LDS16(Wb    + (size_t)(o_base + row) * NC + koff, Abuf + ck * 8);
            GLOAD_LDS16(feats + (size_t)(m_base + row) * NC + koff, Bbuf + ck * 8);
        }
        __syncthreads();
#pragma unroll
        for (int k0 = 0; k0 < 64; k0 += 32) {
            const int cb = (k0 >> 3) + g;
            bf16x8 a[4], b[4];
#pragma unroll
            for (int s = 0; s < 4; ++s) {
                int arow = wo * 64 + s * 16 + l15;
                a[s] = *(const bf16x8*)&Abuf[arow * 64 + ((cb ^ xr) << 3)];
                int brow = wm * 64 + s * 16 + l15;
                b[s] = *(const bf16x8*)&Bbuf[brow * 64 + ((cb ^ xr) << 3)];
            }
#pragma unroll
            for (int os = 0; os < 4; ++os)
#pragma unroll
                for (int ms = 0; ms < 4; ++ms)
                    acc[os][ms] = __builtin_amdgcn_mfma_f32_16x16x32_bf16(a[os], b[ms], acc[os][ms], 0, 0, 0);
        }
        __syncthreads();
    }

#pragma unroll
    for (int os = 0; os < 4; ++os)
#pragma unroll
        for (int ms = 0; ms < 4; ++ms) {
            int m = m_base + wm * 64 + ms * 16 + l15;
            int bb = m / HW2;
            int hw = m - bb * HW2;
            int o = o_base + wo * 64 + os * 16 + g * 4;
            float* dst = out + ((size_t)bb * NO + o) * HW2 + hw;
            f32x4 v = acc[os][ms];
            dst[0 * HW2] = v[0];
            dst[1 * HW2] = v[1];
            dst[2 * HW2] = v[2];
            dst[3 * HW2] = v[3];
        }
}

extern "C" void kernel_launch(void* const* d_in, const int* in_sizes, int n_in,
                              void* d_out, int out_size, void* d_ws, size_t ws_size,
                              hipStream_t stream) {
    const float* x1   = (const float*)d_in[0];
    const float* x3   = (const float*)d_in[1];
    const float* x5   = (const float*)d_in[2];
    const float* W    = (const float*)d_in[3];
    const int*   idx  = (const int*)d_in[4];
    const int*   offh = (const int*)d_in[5];
    const int*   offw = (const int*)d_in[6];
    float* out = (float*)d_out;

    char* ws = (char*)d_ws;
    __bf16* feats  = (__bf16*)(ws);              // 19,267,584 B
    __bf16* Wb     = (__bf16*)(ws + 19267584);   // 589,824 B
    int*    cnt    = (int*)   (ws + 19857408);   // 6,144 B
    int*    pref   = (int*)   (ws + 19863552);   // 6,144 B
    u32*    bucket = (u32*)   (ws + 19869696);   // 786,432 B
    u32*    ent    = (u32*)   (ws + 20656128);   // 301,056 B

    wconv_kernel<<<(NO * NC) / 256, 256, 0, stream>>>(W, Wb, cnt);
    fill_kernel<<<(NC * HW2) / 256, 256, 0, stream>>>(idx, offh, offw, cnt, bucket);
    scan_kernel<<<1, 256, 0, stream>>>(cnt, pref);
    compact_kernel<<<1536, 128, 0, stream>>>(cnt, pref, bucket, ent);
    scatter_kernel<<<384, 512, 0, stream>>>(x1, x3, x5, ent, pref, feats);
    gemm_kernel<<<1176, 256, 0, stream>>>(feats, Wb, out);
}

// Round 19
// 102.320 us; speedup vs baseline: 1.2867x; 1.0835x over previous
//
#include <hip/hip_runtime.h>
#include <hip/hip_bf16.h>

#define PIX 256
#define CROP 14
#define HW2 196
#define BB 128
#define CC 512
#define NC 384
#define NO 768
#define CAP 128

typedef __bf16 bf16x8 __attribute__((ext_vector_type(8)));
typedef __bf16 bf16x4 __attribute__((ext_vector_type(4)));
typedef float  f32x4  __attribute__((ext_vector_type(4)));
typedef unsigned int u32;

#define GLOAD_LDS16(src, dst) \
    __builtin_amdgcn_global_load_lds((const __attribute__((address_space(1))) void*)(src), \
                                     (__attribute__((address_space(3))) void*)(dst), 16, 0, 0)

// wconv + cnt zeroing fused
__global__ void wconv_kernel(const float* __restrict__ W, __bf16* __restrict__ Wb,
                             int* __restrict__ cnt) {
    int tid = blockIdx.x * 256 + threadIdx.x;
    Wb[tid] = (__bf16)W[tid];
    if (tid < 1536) cnt[tid] = 0;
}

// entry word: (c3loc<<25) | (hw<<17) | (p<<9) | ch ; bucket = t*512 + ch
__global__ void fill_kernel(const int* __restrict__ idx, const int* __restrict__ offh,
                            const int* __restrict__ offw, int* __restrict__ cnt,
                            u32* __restrict__ bucket) {
    int tid = blockIdx.x * 256 + threadIdx.x;   // < 75264
    int c3 = tid / HW2;
    int hw = tid - c3 * HW2;
    int i = hw / CROP, j = hw - i * CROP;
    int p = (offh[c3] + i) * 16 + offw[c3] + j;
    int ch = idx[c3 * PIX + p];
    int bkt = (c3 >> 7) * 512 + ch;
    int pos = atomicAdd(&cnt[bkt], 1);
    if (pos < CAP)
        bucket[bkt * CAP + pos] =
            ((u32)(c3 & 127) << 25) | ((u32)hw << 17) | ((u32)p << 9) | (u32)ch;
}

// exclusive prefix over 1536 clamped counts (single block, 6 per thread)
__global__ __launch_bounds__(256) void scan_kernel(const int* __restrict__ cnt,
                                                   int* __restrict__ pref) {
    __shared__ int part[256];
    int tid = threadIdx.x;
    int loc[6];
    int s = 0;
#pragma unroll
    for (int i = 0; i < 6; ++i) {
        int v = cnt[tid * 6 + i]; if (v > CAP) v = CAP;
        loc[i] = s; s += v;
    }
    part[tid] = s;
    __syncthreads();
    if (tid < 64) {
        int l4[4]; int s4 = 0;
#pragma unroll
        for (int i = 0; i < 4; ++i) { l4[i] = s4; s4 += part[tid * 4 + i]; }
        int v = s4;
#pragma unroll
        for (int d = 1; d < 64; d <<= 1) { int u = __shfl_up(v, d); if (tid >= d) v += u; }
        int excl = v - s4;
#pragma unroll
        for (int i = 0; i < 4; ++i) part[tid * 4 + i] = excl + l4[i];
    }
    __syncthreads();
    int off = part[tid];
#pragma unroll
    for (int i = 0; i < 6; ++i) pref[tid * 6 + i] = off + loc[i];
}

// dense entry list ordered (t, ch)
__global__ __launch_bounds__(128) void compact_kernel(const int* __restrict__ cnt,
                                                      const int* __restrict__ pref,
                                                      const u32* __restrict__ bucket,
                                                      u32* __restrict__ ent) {
    int bkt = blockIdx.x;
    int E = cnt[bkt]; if (E > CAP) E = CAP;
    int tid = threadIdx.x;
    if (tid < E) ent[pref[bkt] + tid] = bucket[bkt * CAP + tid];
}

// scatter v14: CONTINUOUS stream. v13's all-coalesced structure, but chunk
// k+1's x-window (2xf32x4/thread) and entry words (4xu32/thread) are
// prefetched into registers WHILE chunk k scatters (T14 issue-early/
// write-late; the post-scatter __syncthreads is the drain). Double-buffered
// bf16 stg removes the read/write hazard. 32 chunks x 16 ch-rows.
// LDS = 50176 (fl) + 2*8192 (stg) + 144 (eb) ~ 66.7KB -> 2 blocks/CU.
__global__ __launch_bounds__(512) void scatter_kernel(
        const float* __restrict__ x1, const float* __restrict__ x3,
        const float* __restrict__ x5, const u32* __restrict__ ent,
        const int* __restrict__ pref, __bf16* __restrict__ feats) {
    __shared__ __bf16 fl[HW2 * 128];         // 50176 B
    __shared__ __bf16 stg[2][16 * 256];      // 2 x 8192 B
    __shared__ int eb[33];
    int d = blockIdx.x;                      // 384 = 8 XCD * 48
    int wg = (d & 7) * 48 + (d >> 3);
    int b = wg / 3, t = wg % 3;
    const float* x = (t == 0) ? x1 : (t == 1) ? x3 : x5;
    const float* xb = x + (size_t)b * CC * PIX;
    int tid = threadIdx.x;

    // chunk entry boundaries (16 ch per chunk)
    if (tid < 33) eb[tid] = (t == 2 && tid == 32) ? 75264 : pref[t * 512 + tid * 16];
    // chunk 0 x-window (independent of eb)
    f32x4 va = *(const f32x4*)(xb + tid * 4);
    f32x4 vb = *(const f32x4*)(xb + 2048 + tid * 4);
    __syncthreads();

    u32 wd[4];
    {
        int e0 = eb[0], e1 = eb[1];
#pragma unroll
        for (int k = 0; k < 4; ++k) {
            int g = e0 + tid + k * 512;
            wd[k] = (g < e1) ? ent[g] : 0xFFFFFFFFu;
        }
        bf16x4 qa, qb;
        qa[0] = (__bf16)va[0]; qa[1] = (__bf16)va[1]; qa[2] = (__bf16)va[2]; qa[3] = (__bf16)va[3];
        qb[0] = (__bf16)vb[0]; qb[1] = (__bf16)vb[1]; qb[2] = (__bf16)vb[2]; qb[3] = (__bf16)vb[3];
        *(bf16x4*)&stg[0][tid * 4] = qa;
        *(bf16x4*)&stg[0][2048 + tid * 4] = qb;
    }
    __syncthreads();

    int cur = 0;
    for (int ck = 0; ck < 32; ++ck) {
        // prefetch chunk ck+1 into registers (in flight during scatter)
        f32x4 na, nb;
        u32 wdn[4];
        if (ck < 31) {
            const float* nx = xb + (ck + 1) * 4096;
            na = *(const f32x4*)(nx + tid * 4);
            nb = *(const f32x4*)(nx + 2048 + tid * 4);
            int ne0 = eb[ck + 1], ne1 = eb[ck + 2];
#pragma unroll
            for (int k = 0; k < 4; ++k) {
                int g = ne0 + tid + k * 512;
                wdn[k] = (g < ne1) ? ent[g] : 0xFFFFFFFFu;
            }
        }
        // scatter chunk ck (LDS -> LDS)
#pragma unroll
        for (int k = 0; k < 4; ++k) {
            u32 w = wd[k];
            if (w != 0xFFFFFFFFu) {
                int ch = w & 511;
                int p  = (w >> 9) & 255;
                int hw = (w >> 17) & 255;
                int c3 = (int)(w >> 25);
                fl[hw * 128 + c3] = stg[cur][(ch & 15) * 256 + p];
            }
        }
        __syncthreads();                     // drains prefetch; scatter done
        if (ck < 31) {
            __bf16* s = stg[cur ^ 1];
            bf16x4 qa, qb;
            qa[0] = (__bf16)na[0]; qa[1] = (__bf16)na[1]; qa[2] = (__bf16)na[2]; qa[3] = (__bf16)na[3];
            qb[0] = (__bf16)nb[0]; qb[1] = (__bf16)nb[1]; qb[2] = (__bf16)nb[2]; qb[3] = (__bf16)nb[3];
            *(bf16x4*)&s[tid * 4] = qa;
            *(bf16x4*)&s[2048 + tid * 4] = qb;
#pragma unroll
            for (int k = 0; k < 4; ++k) wd[k] = wdn[k];
            cur ^= 1;
        }
        __syncthreads();                     // stg ready for next scatter
    }

    // coalesced writeout
    const size_t obase = (size_t)b * HW2 * NC + (size_t)t * 128;
    for (int i2 = tid; i2 < HW2 * 16; i2 += 512) {
        int hw = i2 >> 4, ckk = (i2 & 15) * 8;
        *(bf16x8*)(feats + obase + (size_t)hw * NC + ckk) = *(const bf16x8*)&fl[hw * 128 + ckk];
    }
}

// GEMM: m97 structure, 128x128 tile, BK=64, XOR-swizzled LDS via pre-swizzled source.
__global__ __launch_bounds__(256) void gemm_kernel(const __bf16* __restrict__ feats,
                                                   const __bf16* __restrict__ Wb,
                                                   float* __restrict__ out) {
    __shared__ __bf16 ldsbuf[16384];           // A [128][64] @0, B [128][64] @8192
    __bf16* Abuf = ldsbuf;
    __bf16* Bbuf = ldsbuf + 8192;

    const int d = blockIdx.x;                  // 1176 blocks, 147 per XCD
    const int wg = (d & 7) * 147 + (d >> 3);
    const int o_base = (wg % 6) * 128;
    const int m_base = (wg / 6) * 128;

    const int tid = threadIdx.x;
    const int wave = tid >> 6, lane = tid & 63;
    const int wo = wave >> 1, wm = wave & 1;
    const int l15 = lane & 15, g = lane >> 4;
    const int xr = l15 & 7;

    f32x4 acc[4][4] = {};

    for (int kt = 0; kt < 6; ++kt) {
        const int k0g = kt * 64;
#pragma unroll
        for (int it = 0; it < 4; ++it) {
            int ck = tid + it * 256;
            int row = ck >> 3, cc = ck & 7;
            int koff = k0g + ((cc ^ (row & 7)) << 3);
            GLOAD_LDS16(Wb    + (size_t)(o_base + row) * NC + koff, Abuf + ck * 8);
            GLOAD_LDS16(feats + (size_t)(m_base + row) * NC + koff, Bbuf + ck * 8);
        }
        __syncthreads();
#pragma unroll
        for (int k0 = 0; k0 < 64; k0 += 32) {
            const int cb = (k0 >> 3) + g;
            bf16x8 a[4], b[4];
#pragma unroll
            for (int s = 0; s < 4; ++s) {
                int arow = wo * 64 + s * 16 + l15;
                a[s] = *(const bf16x8*)&Abuf[arow * 64 + ((cb ^ xr) << 3)];
                int brow = wm * 64 + s * 16 + l15;
                b[s] = *(const bf16x8*)&Bbuf[brow * 64 + ((cb ^ xr) << 3)];
            }
#pragma unroll
            for (int os = 0; os < 4; ++os)
#pragma unroll
                for (int ms = 0; ms < 4; ++ms)
                    acc[os][ms] = __builtin_amdgcn_mfma_f32_16x16x32_bf16(a[os], b[ms], acc[os][ms], 0, 0, 0);
        }
        __syncthreads();
    }

#pragma unroll
    for (int os = 0; os < 4; ++os)
#pragma unroll
        for (int ms = 0; ms < 4; ++ms) {
            int m = m_base + wm * 64 + ms * 16 + l15;
            int bb = m / HW2;
            int hw = m - bb * HW2;
            int o = o_base + wo * 64 + os * 16 + g * 4;
            float* dst = out + ((size_t)bb * NO + o) * HW2 + hw;
            f32x4 v = acc[os][ms];
            dst[0 * HW2] = v[0];
            dst[1 * HW2] = v[1];
            dst[2 * HW2] = v[2];
            dst[3 * HW2] = v[3];
        }
}

extern "C" void kernel_launch(void* const* d_in, const int* in_sizes, int n_in,
                              void* d_out, int out_size, void* d_ws, size_t ws_size,
                              hipStream_t stream) {
    const float* x1   = (const float*)d_in[0];
    const float* x3   = (const float*)d_in[1];
    const float* x5   = (const float*)d_in[2];
    const float* W    = (const float*)d_in[3];
    const int*   idx  = (const int*)d_in[4];
    const int*   offh = (const int*)d_in[5];
    const int*   offw = (const int*)d_in[6];
    float* out = (float*)d_out;

    char* ws = (char*)d_ws;
    __bf16* feats  = (__bf16*)(ws);              // 19,267,584 B
    __bf16* Wb     = (__bf16*)(ws + 19267584);   // 589,824 B
    int*    cnt    = (int*)   (ws + 19857408);   // 6,144 B
    int*    pref   = (int*)   (ws + 19863552);   // 6,144 B
    u32*    bucket = (u32*)   (ws + 19869696);   // 786,432 B
    u32*    ent    = (u32*)   (ws + 20656128);   // 301,056 B

    wconv_kernel<<<(NO * NC) / 256, 256, 0, stream>>>(W, Wb, cnt);
    fill_kernel<<<(NC * HW2) / 256, 256, 0, stream>>>(idx, offh, offw, cnt, bucket);
    scan_kernel<<<1, 256, 0, stream>>>(cnt, pref);
    compact_kernel<<<1536, 128, 0, stream>>>(cnt, pref, bucket, ent);
    scatter_kernel<<<384, 512, 0, stream>>>(x1, x3, x5, ent, pref, feats);
    gemm_kernel<<<1176, 256, 0, stream>>>(feats, Wb, out);
}

// Round 20
// 97.384 us; speedup vs baseline: 1.3519x; 1.0507x over previous
//
#include <hip/hip_runtime.h>
#include <hip/hip_bf16.h>

#define PIX 256
#define CROP 14
#define HW2 196
#define BB 128
#define CC 512
#define NC 384
#define NO 768
#define CAP 128
#define EQ 6272       // entries per (t,q) = 128*49

typedef __bf16 bf16x8 __attribute__((ext_vector_type(8)));
typedef float  f32x4  __attribute__((ext_vector_type(4)));
typedef unsigned int u32;

#define GLOAD_LDS16(src, dst) \
    __builtin_amdgcn_global_load_lds((const __attribute__((address_space(1))) void*)(src), \
                                     (__attribute__((address_space(3))) void*)(dst), 16, 0, 0)

// wconv + cnt-zeroing fused
__global__ void wconv_kernel(const float* __restrict__ W, __bf16* __restrict__ Wb,
                             int* __restrict__ cnt) {
    int tid = blockIdx.x * 256 + threadIdx.x;
    Wb[tid] = (__bf16)W[tid];
    if (tid < 6144) cnt[tid] = 0;
}

// entry word: (c3loc<<25) | (hw<<17) | (p<<9) | ch
// bucket index: t*2048 + (hw/49)*512 + ch   (6144 buckets)
__global__ void fill_kernel(const int* __restrict__ idx, const int* __restrict__ offh,
                            const int* __restrict__ offw, int* __restrict__ cnt,
                            u32* __restrict__ bucket) {
    int tid = blockIdx.x * 256 + threadIdx.x;   // < 75264
    int c3 = tid / HW2;
    int hw = tid - c3 * HW2;
    int i = hw / CROP, j = hw - i * CROP;
    int p = (offh[c3] + i) * 16 + offw[c3] + j;
    int ch = idx[c3 * PIX + p];
    int q = hw / 49;
    int bkt = (c3 >> 7) * 2048 + q * 512 + ch;
    int pos = atomicAdd(&cnt[bkt], 1);
    if (pos < CAP)
        bucket[bkt * CAP + pos] =
            ((u32)(c3 & 127) << 25) | ((u32)hw << 17) | ((u32)p << 9) | (u32)ch;
}

// exclusive prefix over 6144 clamped counts (single block, 24 per thread)
__global__ __launch_bounds__(256) void scan_kernel(const int* __restrict__ cnt,
                                                   int* __restrict__ pref) {
    __shared__ int part[256];
    int tid = threadIdx.x;
    int loc[24];
    int s = 0;
#pragma unroll
    for (int i = 0; i < 24; ++i) {
        int v = cnt[tid * 24 + i]; if (v > CAP) v = CAP;
        loc[i] = s; s += v;
    }
    part[tid] = s;
    __syncthreads();
    if (tid < 64) {
        int l4[4]; int s4 = 0;
#pragma unroll
        for (int i = 0; i < 4; ++i) { l4[i] = s4; s4 += part[tid * 4 + i]; }
        int v = s4;
#pragma unroll
        for (int d = 1; d < 64; d <<= 1) { int u = __shfl_up(v, d); if (tid >= d) v += u; }
        int excl = v - s4;
#pragma unroll
        for (int i = 0; i < 4; ++i) part[tid * 4 + i] = excl + l4[i];
    }
    __syncthreads();
    int off = part[tid];
#pragma unroll
    for (int i = 0; i < 24; ++i) pref[tid * 24 + i] = off + loc[i];
}

// dense entry list, ordered (t, q, ch); base of (t,q) = (t*4+q)*6272 exactly
__global__ __launch_bounds__(128) void compact_kernel(const int* __restrict__ cnt,
                                                      const int* __restrict__ pref,
                                                      const u32* __restrict__ bucket,
                                                      u32* __restrict__ ent) {
    int bkt = blockIdx.x;
    int E = cnt[bkt]; if (E > CAP) E = CAP;
    int tid = threadIdx.x;
    if (tid < E) ent[pref[bkt] + tid] = bucket[bkt * CAP + tid];
}

// scatter (R13/R15 best): block = (b, t, hw-quarter q): 1536 blocks,
// LDS 12.5KB, ~6 blocks/CU. Sequential ch-sorted sweep of x[b], LDS tile
// fl[49][128] (each cell exactly once), coalesced writeout to feats.
// Service-rate bound ~79us (13 structural variants ablated null, R4-R18).
__global__ __launch_bounds__(256) void scatter_kernel(
        const float* __restrict__ x1, const float* __restrict__ x3,
        const float* __restrict__ x5, const u32* __restrict__ ent,
        __bf16* __restrict__ feats) {
    __shared__ __bf16 fl[49 * 128];          // 12544 B
    int d = blockIdx.x;                      // 1536 = 8 XCD * 192
    int wg = (d & 7) * 192 + (d >> 3);
    int b = wg / 12, tq = wg - b * 12;
    int t = tq >> 2, q = tq & 3;
    const float* x = (t == 0) ? x1 : (t == 1) ? x3 : x5;
    const float* xb = x + (size_t)b * CC * PIX;
    const u32* el = ent + tq * EQ;
    int tid = threadIdx.x;

    for (int g = tid; g < EQ; g += 256) {
        u32 wd = el[g];                      // coalesced, ascending ch
        int ch = wd & 511;
        int p  = (wd >> 9) & 255;
        int hw = (wd >> 17) & 255;
        int c3 = wd >> 25;
        float f = xb[ch * PIX + p];
        fl[(hw - q * 49) * 128 + c3] = (__bf16)f;
    }
    __syncthreads();

    const size_t obase = ((size_t)b * HW2 + q * 49) * NC + (size_t)t * 128;
    for (int i2 = tid; i2 < 49 * 16; i2 += 256) {
        int hwl = i2 >> 4, ck = (i2 & 15) * 8;
        *(bf16x8*)(feats + obase + (size_t)hwl * NC + ck) = *(const bf16x8*)&fl[hwl * 128 + ck];
    }
}

// GEMM: m97 structure, 128x128 tile, BK=64, XOR-swizzled LDS via pre-swizzled source.
__global__ __launch_bounds__(256) void gemm_kernel(const __bf16* __restrict__ feats,
                                                   const __bf16* __restrict__ Wb,
                                                   float* __restrict__ out) {
    __shared__ __bf16 ldsbuf[16384];           // A [128][64] @0, B [128][64] @8192
    __bf16* Abuf = ldsbuf;
    __bf16* Bbuf = ldsbuf + 8192;

    const int d = blockIdx.x;                  // 1176 blocks, 147 per XCD
    const int wg = (d & 7) * 147 + (d >> 3);
    const int o_base = (wg % 6) * 128;
    const int m_base = (wg / 6) * 128;

    const int tid = threadIdx.x;
    const int wave = tid >> 6, lane = tid & 63;
    const int wo = wave >> 1, wm = wave & 1;
    const int l15 = lane & 15, g = lane >> 4;
    const int xr = l15 & 7;

    f32x4 acc[4][4] = {};

    for (int kt = 0; kt < 6; ++kt) {
        const int k0g = kt * 64;
#pragma unroll
        for (int it = 0; it < 4; ++it) {
            int ck = tid + it * 256;
            int row = ck >> 3, cc = ck & 7;
            int koff = k0g + ((cc ^ (row & 7)) << 3);
            GLOAD_LDS16(Wb    + (size_t)(o_base + row) * NC + koff, Abuf + ck * 8);
            GLOAD_LDS16(feats + (size_t)(m_base + row) * NC + koff, Bbuf + ck * 8);
        }
        __syncthreads();
#pragma unroll
        for (int k0 = 0; k0 < 64; k0 += 32) {
            const int cb = (k0 >> 3) + g;
            bf16x8 a[4], b[4];
#pragma unroll
            for (int s = 0; s < 4; ++s) {
                int arow = wo * 64 + s * 16 + l15;
                a[s] = *(const bf16x8*)&Abuf[arow * 64 + ((cb ^ xr) << 3)];
                int brow = wm * 64 + s * 16 + l15;
                b[s] = *(const bf16x8*)&Bbuf[brow * 64 + ((cb ^ xr) << 3)];
            }
#pragma unroll
            for (int os = 0; os < 4; ++os)
#pragma unroll
                for (int ms = 0; ms < 4; ++ms)
                    acc[os][ms] = __builtin_amdgcn_mfma_f32_16x16x32_bf16(a[os], b[ms], acc[os][ms], 0, 0, 0);
        }
        __syncthreads();
    }

#pragma unroll
    for (int os = 0; os < 4; ++os)
#pragma unroll
        for (int ms = 0; ms < 4; ++ms) {
            int m = m_base + wm * 64 + ms * 16 + l15;
            int bb = m / HW2;
            int hw = m - bb * HW2;
            int o = o_base + wo * 64 + os * 16 + g * 4;
            float* dst = out + ((size_t)bb * NO + o) * HW2 + hw;
            f32x4 v = acc[os][ms];
            dst[0 * HW2] = v[0];
            dst[1 * HW2] = v[1];
            dst[2 * HW2] = v[2];
            dst[3 * HW2] = v[3];
        }
}

extern "C" void kernel_launch(void* const* d_in, const int* in_sizes, int n_in,
                              void* d_out, int out_size, void* d_ws, size_t ws_size,
                              hipStream_t stream) {
    const float* x1   = (const float*)d_in[0];
    const float* x3   = (const float*)d_in[1];
    const float* x5   = (const float*)d_in[2];
    const float* W    = (const float*)d_in[3];
    const int*   idx  = (const int*)d_in[4];
    const int*   offh = (const int*)d_in[5];
    const int*   offw = (const int*)d_in[6];
    float* out = (float*)d_out;

    char* ws = (char*)d_ws;
    __bf16* feats  = (__bf16*)(ws);              // 19,267,584 B
    __bf16* Wb     = (__bf16*)(ws + 19267584);   // 589,824 B
    int*    cnt    = (int*)   (ws + 19857408);   // 24,576 B
    int*    pref   = (int*)   (ws + 19881984);   // 24,576 B
    u32*    bucket = (u32*)   (ws + 19906560);   // 3,145,728 B
    u32*    ent    = (u32*)   (ws + 23052288);   // 301,056 B

    wconv_kernel<<<(NO * NC) / 256, 256, 0, stream>>>(W, Wb, cnt);
    fill_kernel<<<(NC * HW2) / 256, 256, 0, stream>>>(idx, offh, offw, cnt, bucket);
    scan_kernel<<<1, 256, 0, stream>>>(cnt, pref);
    compact_kernel<<<6144, 128, 0, stream>>>(cnt, pref, bucket, ent);
    scatter_kernel<<<1536, 256, 0, stream>>>(x1, x3, x5, ent, feats);
    gemm_kernel<<<1176, 256, 0, stream>>>(feats, Wb, out);
}